// Round 16
// baseline (98.086 us; speedup 1.0000x reference)
//
#include <hip/hip_runtime.h>
#include <hip/hip_bf16.h>

typedef __attribute__((ext_vector_type(4))) float  f4;
typedef __attribute__((ext_vector_type(8))) short  short8;
typedef __attribute__((ext_vector_type(4))) float  f32x4;

static constexpr int NHEAD = 16;
static constexpr int NIN   = 128;
static constexpr int NOUT  = 128;
static constexpr int NROWS = 8 * 2048;          // B*S = 16384
static constexpr int RSTR  = NHEAD * NIN;       // 2048 floats (8KB) per (b,s) row
static constexpr int ROWS_PER_STEP  = 32;       // per WG per loop step
static constexpr int STEPS          = 8;
static constexpr int ROWS_PER_BLOCK = ROWS_PER_STEP * STEPS;   // 256
static constexpr int BLOCKS_X = NROWS / ROWS_PER_BLOCK;        // 64 -> 1024 WGs = 4/CU

// No LDS, no barriers: W fragments live in registers (8 frags = 32 VGPR per
// wave); 4 WGs/CU x 8 waves = 32 waves/CU of fully independent streaming —
// the m13-copy regime. Six LDS/barrier-coupled variants all hit >=52us with
// all pipes idle; this removes the coupling entirely.

static __device__ inline unsigned short f2bfu(float f) {
  union { __hip_bfloat16 h; unsigned short u; } v;
  v.h = __float2bfloat16(f);
  return v.u;
}

static __device__ inline short8 cvt8(f4 a, f4 b) {
  short8 r;
  r[0] = (short)f2bfu(a[0]); r[1] = (short)f2bfu(a[1]);
  r[2] = (short)f2bfu(a[2]); r[3] = (short)f2bfu(a[3]);
  r[4] = (short)f2bfu(b[0]); r[5] = (short)f2bfu(b[1]);
  r[6] = (short)f2bfu(b[2]); r[7] = (short)f2bfu(b[3]);
  return r;
}

__global__ __launch_bounds__(512, 4)   // VGPR cap 128; 4 WGs/CU thread-capped
void bdp_kernel(const float* __restrict__ X, const float* __restrict__ W,
                float* __restrict__ O) {
  const int head = blockIdx.y;
  const int tid  = (int)threadIdx.x;
  const int lane = tid & 63;
  const int wid  = tid >> 6;      // 8 waves
  const int lr   = lane & 15;
  const int lq   = lane >> 4;
  const int rg   = wid & 1;       // row-group (16 rows) within 32-row step
  const int nh   = wid >> 1;      // col-pair: n in {2nh, 2nh+1}

  // ---- W fragments -> REGISTERS (once per WG; A-operand layout:
  // lane holds o = n*16 + lr, k = kk*32 + lq*8 + j) ----
  const float* Wh = W + (size_t)head * NOUT * NIN;
  short8 wf0[4], wf1[4];          // n = 2nh, 2nh+1; kk = 0..3
  #pragma unroll
  for (int kk = 0; kk < 4; ++kk) {
    const float* s0 = Wh + ((2 * nh + 0) * 16 + lr) * NIN + kk * 32 + lq * 8;
    const float* s1 = Wh + ((2 * nh + 1) * 16 + lr) * NIN + kk * 32 + lq * 8;
    wf0[kk] = cvt8(*reinterpret_cast<const f4*>(s0),
                   *reinterpret_cast<const f4*>(s0 + 4));
    wf1[kk] = cvt8(*reinterpret_cast<const f4*>(s1),
                   *reinterpret_cast<const f4*>(s1 + 4));
  }

  const int rowbase = (int)blockIdx.x * ROWS_PER_BLOCK + rg * 16;
  // this lane's X row pointer (row = rowbase + step*32 + lr), head column slice
  const float* xr = X + (size_t)(rowbase + lr) * RSTR + head * NIN;
  float* orow     = O + (size_t)(rowbase + lr) * RSTR + head * NOUT;

  for (int t = 0; t < STEPS; ++t) {
    const float* xt = xr + (size_t)t * ROWS_PER_STEP * RSTR;

    f32x4 acc0 = (f32x4){0.f, 0.f, 0.f, 0.f};
    f32x4 acc1 = (f32x4){0.f, 0.f, 0.f, 0.f};
    #pragma unroll
    for (int kk = 0; kk < 4; ++kk) {
      const int koff = kk * 32 + lq * 8;
      f4 a = *reinterpret_cast<const f4*>(xt + koff);
      f4 b = *reinterpret_cast<const f4*>(xt + koff + 4);
      short8 xv = cvt8(a, b);   // B frag: col = x-row = lr, k = koff..+7
      acc0 = __builtin_amdgcn_mfma_f32_16x16x32_bf16(wf0[kk], xv, acc0, 0, 0, 0);
      acc1 = __builtin_amdgcn_mfma_f32_16x16x32_bf16(wf1[kk], xv, acc1, 0, 0, 0);
    }

    // D[o][xrow]: xrow = lane&15, o = n*16 + lq*4 + reg; acc0+acc1 pair
    // covers bytes nh*128 .. nh*128+127 per row -> full-line write combining.
    float* dst = orow + (size_t)t * ROWS_PER_STEP * RSTR;
    *reinterpret_cast<f4*>(dst + (2 * nh + 0) * 16 + lq * 4) = acc0;
    *reinterpret_cast<f4*>(dst + (2 * nh + 1) * 16 + lq * 4) = acc1;
  }
}

extern "C" void kernel_launch(void* const* d_in, const int* in_sizes, int n_in,
                              void* d_out, int out_size, void* d_ws, size_t ws_size,
                              hipStream_t stream) {
  const float* X = (const float*)d_in[0];   // [8,2048,16,128] f32
  const float* W = (const float*)d_in[1];   // [16,128,128] f32
  float* O = (float*)d_out;                 // [8,2048,16,128] f32
  dim3 grid(BLOCKS_X, NHEAD);
  bdp_kernel<<<grid, dim3(512), 0, stream>>>(X, W, O);
}